// Round 16
// baseline (167.581 us; speedup 1.0000x reference)
//
#include <hip/hip_runtime.h>
#include <cstddef>

#define N_TOK 2048
#define BATCH 2
#define EMB   1024
#define NH    16
#define HD    64
#define NP    16
#define BHN   32
#define CHK   64
#define NCHK  32
#define SCALING 0.125f

typedef __attribute__((ext_vector_type(8))) short short8;
typedef __attribute__((ext_vector_type(4))) float f32x4;

typedef __attribute__((address_space(1))) const void gvoid;
typedef __attribute__((address_space(3))) void lvoid;
__device__ __forceinline__ void gload16(const void* g, void* l) {
  __builtin_amdgcn_global_load_lds((gvoid*)g, (lvoid*)l, 16, 0, 0);
}

__device__ __forceinline__ unsigned short f2bf(float f) {
  unsigned u = __float_as_uint(f);
  u += 0x7FFFu + ((u >> 16) & 1u);
  return (unsigned short)(u >> 16);
}
__device__ __forceinline__ float bf2f(unsigned short b) {
  return __uint_as_float((unsigned)b << 16);
}

// ---------------- L1: fused prep (bf16 converts + concat) + pq projection ----------------
__global__ __launch_bounds__(256) void prep_pq_kernel(
    const float* __restrict__ query, const float* __restrict__ Wk,
    const float* __restrict__ Wv, const float* __restrict__ Wo,
    const float* __restrict__ bk, const float* __restrict__ bv,
    const float* __restrict__ pquery, const float* __restrict__ Wpq,
    const float* __restrict__ bpq,
    unsigned short* __restrict__ qbf, unsigned short* __restrict__ wkvbf,
    unsigned short* __restrict__ wobf, float* __restrict__ bkv,
    unsigned short* __restrict__ pq_sb, unsigned* __restrict__ cnt)
{
  const int b = blockIdx.x, t = threadIdx.x;
  if (b < 512) {
    __shared__ float xs[EMB];
    __shared__ float part[4][64];
    const int r = b >> 4, seg = b & 15;
    const int p = r >> 1, ib = r & 1;
    const int el = t & 63, ks = t >> 6;
    const int e = seg * 64 + el;
    for (int l = t; l < EMB; l += 256) xs[l] = pquery[(size_t)r * EMB + l];
    __syncthreads();
    const float* wrow = &Wpq[(size_t)e * EMB + ks * 256];
    const float* xp = &xs[ks * 256];
    float acc = 0.f;
    #pragma unroll 8
    for (int cc = 0; cc < 256; cc += 4) {
      const float4 w4 = *(const float4*)&wrow[cc];
      acc += xp[cc] * w4.x + xp[cc + 1] * w4.y + xp[cc + 2] * w4.z + xp[cc + 3] * w4.w;
    }
    part[ks][el] = acc;
    __syncthreads();
    if (ks == 0) {
      float s = part[0][el] + part[1][el] + part[2][el] + part[3][el];
      s = (s + bpq[e]) * SCALING;
      const int h = e >> 6, d = e & 63;
      pq_sb[((size_t)(ib * NH + h) * NP + p) * HD + d] = f2bf(s);
    }
  } else {
    if (b == 512 && t < BHN) cnt[t] = 0;   // reset last-block counters each call
    const int tid = (b - 512) * 256 + t;
    const int NT = 1024 * 256;
    for (int i = tid; i < 1835008; i += NT) {
      const float* src; unsigned short* dst; int off;
      if (i < 1048576)      { src = query; dst = qbf;             off = i; }
      else if (i < 1310720) { src = Wk;    dst = wkvbf;           off = i - 1048576; }
      else if (i < 1572864) { src = Wv;    dst = wkvbf + 1048576; off = i - 1310720; }
      else                  { src = Wo;    dst = wobf;            off = i - 1572864; }
      const float4 v = *(const float4*)&src[(size_t)off * 4];
      ushort4 o;
      o.x = f2bf(v.x); o.y = f2bf(v.y); o.z = f2bf(v.z); o.w = f2bf(v.w);
      *(ushort4*)&dst[(size_t)off * 4] = o;
    }
    if (tid < 512) {
      const int j = tid * 4;
      if (j < 1024) *(float4*)&bkv[j] = *(const float4*)&bk[j];
      else          *(float4*)&bkv[j] = *(const float4*)&bv[j - 1024];
    }
  }
}

// ---------------- KV GEMM: 128x128 tiles, double-buffered, dual bf16 out ----------------
__global__ __launch_bounds__(256) void kv_gemm_kernel(
    const unsigned short* __restrict__ Xb, const unsigned short* __restrict__ Wb,
    const float* __restrict__ bias, unsigned short* __restrict__ Y0,
    unsigned short* __restrict__ Y1)
{
  __shared__ unsigned short As[2][4096];
  __shared__ unsigned short Bs[2][4096];
  const int t = threadIdx.x;
  const int L = blockIdx.x;
  const int b = (L & 7) * 64 + (L >> 3);            // XCD-bijective swizzle (512 % 8 == 0)
  const int m0 = (b >> 4) * 128, n0 = (b & 15) * 128;
  const int lane = t & 63, w = t >> 6, wr = w >> 1, wc = w & 1;
  const int lr = lane & 15, lg = lane >> 4;
  const int srow = t >> 2, scol = (t & 3) << 3;
  const unsigned short* xa = &Xb[(size_t)(m0 + srow) * 1024 + scol];
  const unsigned short* xc = xa + (size_t)64 * 1024;
  const unsigned short* wp = &Wb[(size_t)(n0 + srow) * 1024 + scol];
  const unsigned short* wq = wp + (size_t)64 * 1024;
  f32x4 acc[4][4] = {};

  gload16(xa, &As[0][t * 8]);
  gload16(xc, &As[0][2048 + t * 8]);
  gload16(wp, &Bs[0][t * 8]);
  gload16(wq, &Bs[0][2048 + t * 8]);
  __syncthreads();
  int cur = 0;
  for (int ks = 0; ks < 32; ++ks) {
    if (ks < 31) {
      const int k1 = (ks + 1) * 32;
      gload16(xa + k1, &As[cur ^ 1][t * 8]);
      gload16(xc + k1, &As[cur ^ 1][2048 + t * 8]);
      gload16(wp + k1, &Bs[cur ^ 1][t * 8]);
      gload16(wq + k1, &Bs[cur ^ 1][2048 + t * 8]);
    }
    short8 av[4], bv[4];
    #pragma unroll
    for (int m = 0; m < 4; ++m) av[m] = *(const short8*)&As[cur][(wr * 64 + m * 16 + lr) * 32 + lg * 8];
    #pragma unroll
    for (int n = 0; n < 4; ++n) bv[n] = *(const short8*)&Bs[cur][(wc * 64 + n * 16 + lr) * 32 + lg * 8];
    #pragma unroll
    for (int m = 0; m < 4; ++m)
      #pragma unroll
      for (int n = 0; n < 4; ++n)
        acc[m][n] = __builtin_amdgcn_mfma_f32_16x16x32_bf16(av[m], bv[n], acc[m][n], 0, 0, 0);
    __syncthreads();
    cur ^= 1;
  }

  // epilogue: stage tile into LDS (rows 0-63 -> As, 64-127 -> Bs), then uint4 stores
  unsigned short* reg = (wr == 0) ? &As[0][0] : &Bs[0][0];
  #pragma unroll
  for (int n = 0; n < 4; ++n) {
    const int cl = wc * 64 + n * 16 + lr;
    const float bcol = bias[n0 + cl];
    #pragma unroll
    for (int m = 0; m < 4; ++m) {
      const int rl = (m * 16 + lg * 4);
      #pragma unroll
      for (int q = 0; q < 4; ++q)
        reg[(rl + q) * 128 + cl] = f2bf(acc[m][n][q] + bcol);
    }
  }
  __syncthreads();
  unsigned short* dd = (n0 < 1024) ? Y0 : Y1;
  const int n0l = n0 & 1023;
  const int chunk = t & 15;
  #pragma unroll
  for (int pass = 0; pass < 8; ++pass) {
    const int row = pass * 16 + (t >> 4);
    const unsigned short* rg = (row < 64) ? &As[0][0] : &Bs[0][0];
    const uint4 v = *(const uint4*)&rg[(row & 63) * 128 + chunk * 8];
    *(uint4*)&dd[(size_t)(m0 + row) * 1024 + n0l + chunk * 8] = v;
  }
}

// ---------------- fused pattn (MFMA) + exp + per-chunk totals + last-block scan ----------------
__global__ __launch_bounds__(256) void pattn_totals_kernel(
    const unsigned short* __restrict__ qbf, const unsigned short* __restrict__ pq_sb,
    const unsigned short* __restrict__ Kbf, const unsigned short* __restrict__ Vbf,
    unsigned short* __restrict__ peb, unsigned short* __restrict__ Tkb,
    unsigned short* __restrict__ Tvb, float* __restrict__ Tsc,
    unsigned* __restrict__ cnt)
{
  const int c = blockIdx.x, bh = blockIdx.y;
  const int ib = bh >> 4, h = bh & 15;
  const int t = threadIdx.x;
  const int i0 = c * CHK;
  const int lane = t & 63, w = t >> 6;
  const int lr = lane & 15, lg = lane >> 4;
  const int wrow = w * 16;

  __shared__ unsigned short KT[64][80];   // [d][j]
  __shared__ unsigned short VT[64][80];   // [d][j]
  __shared__ unsigned short EbT[16][80];  // [p][j]
  __shared__ float Ef[64][20];            // [j][p]
  __shared__ float tspart[4][16];
  __shared__ unsigned lastflag;

  #pragma unroll
  for (int it = 0; it < 2; ++it) {
    const int task = t + it * 256;
    const int j = task & 63, dg = task >> 6;
    const size_t g = ((size_t)(i0 + j) * BATCH + ib) * EMB + h * HD + dg * 8;
    const uint4 ku = *(const uint4*)&Kbf[g];
    const uint4 vu = *(const uint4*)&Vbf[g];
    const unsigned short* kk = (const unsigned short*)&ku;
    const unsigned short* vv = (const unsigned short*)&vu;
    #pragma unroll
    for (int e = 0; e < 8; ++e) { KT[dg * 8 + e][j] = kk[e]; VT[dg * 8 + e][j] = vv[e]; }
  }

  // logits via MFMA
  {
    const size_t qg = ((size_t)(i0 + wrow + lr) * BATCH + ib) * EMB + h * HD;
    short8 avq0 = *(const short8*)&qbf[qg + lg * 8];
    short8 avq1 = *(const short8*)&qbf[qg + 32 + lg * 8];
    const size_t pb = (size_t)bh * 1024 + (size_t)lr * 64;
    short8 bp0 = *(const short8*)&pq_sb[pb + lg * 8];
    short8 bp1 = *(const short8*)&pq_sb[pb + 32 + lg * 8];
    f32x4 lacc = {};
    lacc = __builtin_amdgcn_mfma_f32_16x16x32_bf16(avq0, bp0, lacc, 0, 0, 0);
    lacc = __builtin_amdgcn_mfma_f32_16x16x32_bf16(avq1, bp1, lacc, 0, 0, 0);
    #pragma unroll
    for (int q = 0; q < 4; ++q) {
      const int i = wrow + lg * 4 + q;
      const float e = expf(lacc[q]);
      const unsigned short eb = f2bf(e);
      peb[(size_t)bh * (N_TOK * NP) + (size_t)(i0 + i) * NP + lr] = eb;
      Ef[i][lr] = e;
      EbT[lr][i] = eb;
    }
  }
  __syncthreads();

  if (t < 64) {
    const int p = t & 15, qq = t >> 4;
    float s = 0.f;
    #pragma unroll
    for (int jj = 0; jj < 16; ++jj) s += Ef[qq * 16 + jj][p];
    tspart[qq][p] = s;
  }

  short8 ae0 = *(const short8*)&EbT[lr][lg * 8];
  short8 ae1 = *(const short8*)&EbT[lr][32 + lg * 8];
  const size_t tb = (size_t)(bh * NCHK + c) * 1024;

  {  // Tk raw, [p][d] layout, bf16
    f32x4 ka = {};
    short8 bk0 = *(const short8*)&KT[w * 16 + lr][lg * 8];
    short8 bk1 = *(const short8*)&KT[w * 16 + lr][32 + lg * 8];
    ka = __builtin_amdgcn_mfma_f32_16x16x32_bf16(ae0, bk0, ka, 0, 0, 0);
    ka = __builtin_amdgcn_mfma_f32_16x16x32_bf16(ae1, bk1, ka, 0, 0, 0);
    #pragma unroll
    for (int q = 0; q < 4; ++q) Tkb[tb + (lg * 4 + q) * 64 + w * 16 + lr] = f2bf(ka[q]);
  }
  {  // Tv raw, [d][p] layout, bf16
    f32x4 va = {};
    short8 av0 = *(const short8*)&VT[w * 16 + lr][lg * 8];
    short8 av1 = *(const short8*)&VT[w * 16 + lr][32 + lg * 8];
    va = __builtin_amdgcn_mfma_f32_16x16x32_bf16(av0, ae0, va, 0, 0, 0);
    va = __builtin_amdgcn_mfma_f32_16x16x32_bf16(av1, ae1, va, 0, 0, 0);
    #pragma unroll
    for (int q = 0; q < 4; ++q) Tvb[tb + (w * 16 + lg * 4 + q) * 16 + lr] = f2bf(va[q]);
  }
  __syncthreads();
  if (t < 16)
    Tsc[(size_t)(bh * NCHK + c) * 16 + t] =
        tspart[0][t] + tspart[1][t] + tspart[2][t] + tspart[3][t];

  // ---- publish totals; the last-arriving block of this bh performs the scan
  __syncthreads();                       // all block stores drained to L2
  if (t == 0) {
    __threadfence();                     // flush this XCD's L2 to memory (release)
    lastflag = atomicAdd(&cnt[bh], 1u);  // device-scope
  }
  __syncthreads();
  if (lastflag == NCHK - 1) {
    __threadfence();                     // acquire: order reads after the atomic
    #pragma unroll
    for (int s = 0; s < 8; ++s) {
      const int slot = t + s * 256;
      unsigned short* arr = (slot < 1024) ? Tkb : Tvb;
      const int e = slot & 1023;
      const size_t base = (size_t)bh * (NCHK * 1024) + e;
      float run = 0.f;
      #pragma unroll
      for (int c2 = 0; c2 < NCHK; ++c2) {
        const float v = bf2f(arr[base + (size_t)c2 * 1024]);
        arr[base + (size_t)c2 * 1024] = f2bf(run);
        run += v;
      }
    }
    if (t < 16) {
      const size_t sb = (size_t)bh * (NCHK * 16) + t;
      float rs = 0.f;
      #pragma unroll
      for (int c2 = 0; c2 < NCHK; ++c2) {
        const float sv = Tsc[sb + c2 * 16];
        Tsc[sb + c2 * 16] = rs;
        rs += sv;
      }
    }
  }
}

// ---------------- within-chunk causal attention via MFMA (register-direct operands) ----------------
__global__ __launch_bounds__(256) void attn_mfma_kernel(
    const unsigned short* __restrict__ qbf, const unsigned short* __restrict__ Kbf,
    const unsigned short* __restrict__ Vbf, const unsigned short* __restrict__ peb,
    const unsigned short* __restrict__ Tkb, const unsigned short* __restrict__ Tvb,
    const float* __restrict__ Ts, unsigned short* __restrict__ aw_bufb,
    unsigned short* __restrict__ outpre)
{
  const int c = blockIdx.x, bh = blockIdx.y;
  const int ib = bh >> 4, h = bh & 15;
  const int t = threadIdx.x;
  const int i0 = c * CHK;
  const int lane = t & 63, w = t >> 6;
  const int ws = w * 16;
  const int lr = lane & 15, lg = lane >> 4;
  const int nsl = (w >> 1) + 1;
  const short8 zero8 = {0, 0, 0, 0, 0, 0, 0, 0};

  __shared__ unsigned short VT[64][80];    // [d][j]; reused as out-tile at the end
  __shared__ unsigned short Ab[64][80];
  __shared__ unsigned short EbT[16][80];
  __shared__ unsigned short Gb[64][40];

  const size_t qg = ((size_t)(i0 + ws + lr) * BATCH + ib) * EMB + h * HD;
  short8 avq0 = *(const short8*)&qbf[qg + lg * 8];
  short8 avq1 = *(const short8*)&qbf[qg + 32 + lg * 8];

  #pragma unroll
  for (int it = 0; it < 2; ++it) {
    const int task = t + it * 256;
    const int j = task & 63, dg = task >> 6;
    const size_t g = ((size_t)(i0 + j) * BATCH + ib) * EMB + h * HD + dg * 8;
    const uint4 vu = *(const uint4*)&Vbf[g];
    const unsigned short* vv = (const unsigned short*)&vu;
    #pragma unroll
    for (int e = 0; e < 8; ++e) VT[dg * 8 + e][j] = vv[e];
  }
  {
    const int j = t >> 2, p0 = (t & 3) << 2;
    const ushort4 e4 = *(const ushort4*)&peb[(size_t)bh * (N_TOK * NP) + (size_t)(i0 + j) * NP + p0];
    EbT[p0][j] = e4.x; EbT[p0 + 1][j] = e4.y; EbT[p0 + 2][j] = e4.z; EbT[p0 + 3][j] = e4.w;
  }
  __syncthreads();

  f32x4 sacc[4] = {};
  #pragma unroll
  for (int n = 0; n < 4; ++n) {
    const size_t kg = ((size_t)(i0 + n * 16 + lr) * BATCH + ib) * EMB + h * HD;
    short8 bk0 = *(const short8*)&Kbf[kg + lg * 8];
    short8 bk1 = *(const short8*)&Kbf[kg + 32 + lg * 8];
    if (n <= w) {
      sacc[n] = __builtin_amdgcn_mfma_f32_16x16x32_bf16(avq0, bk0, sacc[n], 0, 0, 0);
      sacc[n] = __builtin_amdgcn_mfma_f32_16x16x32_bf16(avq1, bk1, sacc[n], 0, 0, 0);
    }
  }
  #pragma unroll
  for (int q = 0; q < 4; ++q)
    if (lr >= lg * 4 + q) sacc[w][q] = 0.f;
  for (int n = 0; n < 2 * nsl; ++n)
    #pragma unroll
    for (int q = 0; q < 4; ++q)
      Ab[ws + lg * 4 + q][n * 16 + lr] = f2bf(sacc[n][q]);

  short8 bve0 = *(const short8*)&EbT[lr][lg * 8];
  short8 bve1 = *(const short8*)&EbT[lr][32 + lg * 8];

  f32x4 wacc = {};
  {
    const size_t nb = (size_t)(bh * NCHK + c) * 1024 + (size_t)lr * 64 + lg * 8;
    short8 bn0 = *(const short8*)&Tkb[nb];
    short8 bn1 = *(const short8*)&Tkb[nb + 32];
    wacc = __builtin_amdgcn_mfma_f32_16x16x32_bf16(avq0, bn0, wacc, 0, 0, 0);
    wacc = __builtin_amdgcn_mfma_f32_16x16x32_bf16(avq1, bn1, wacc, 0, 0, 0);
  }
  for (int ks = 0; ks < nsl; ++ks) {
    short8 aa = *(const short8*)&Ab[ws + lr][ks * 32 + lg * 8];
    wacc = __builtin_amdgcn_mfma_f32_16x16x32_bf16(aa, ks ? bve1 : bve0, wacc, 0, 0, 0);
  }
  const float s0 = Ts[(size_t)(bh * NCHK + c) * 16 + lr];
  f32x4 scacc = {s0, s0, s0, s0};
  for (int ks = 0; ks < nsl; ++ks) {
    const int jb = ks * 32 + lg * 8;
    const int irow = ws + lr;
    short8 ones;
    #pragma unroll
    for (int e = 0; e < 8; ++e) ones[e] = (short)((jb + e < irow) ? 0x3F80 : 0);
    scacc = __builtin_amdgcn_mfma_f32_16x16x32_bf16(ones, ks ? bve1 : bve0, scacc, 0, 0, 0);
  }

  const size_t awbase = (size_t)bh * (N_TOK * NP) + (size_t)i0 * NP;
  #pragma unroll
  for (int q = 0; q < 4; ++q) {
    const int il = lg * 4 + q;
    const float ssum = scacc[q];
    const float ssafe = (ssum > 0.f) ? ssum : 1.f;
    const float wv = SCALING * wacc[q] / ssafe;
    float m = wv;
    #pragma unroll
    for (int off = 1; off < 16; off <<= 1) m = fmaxf(m, __shfl_xor(m, off, 64));
    const float e = expf(wv - m);
    float ss = e;
    #pragma unroll
    for (int off = 1; off < 16; off <<= 1) ss += __shfl_xor(ss, off, 64);
    const float aw = e / ss;
    aw_bufb[awbase + (size_t)(ws + il) * NP + lr] = f2bf(aw);
    const float g = aw / ssafe;
    Gb[ws + il][lr] = f2bf(g);
    Gb[ws + il][lr + 16] = 0;
  }

  short8 ga = *(const short8*)&Gb[ws + lr][lg * 8];
  f32x4 bacc[4] = {};
  #pragma unroll
  for (int n = 0; n < 4; ++n) {
    const size_t eg = (size_t)bh * (N_TOK * NP) + (size_t)(i0 + n * 16 + lr) * NP + (lg & 1) * 8;
    short8 bl = *(const short8*)&peb[eg];
    short8 be = (lg < 2) ? bl : zero8;
    if (n <= w)
      bacc[n] = __builtin_amdgcn_mfma_f32_16x16x32_bf16(ga, be, bacc[n], 0, 0, 0);
  }
  #pragma unroll
  for (int q = 0; q < 4; ++q)
    if (lr >= lg * 4 + q) bacc[w][q] = 0.f;
  for (int n = 0; n < 2 * nsl; ++n)
    #pragma unroll
    for (int q = 0; q < 4; ++q)
      Ab[ws + lg * 4 + q][n * 16 + lr] = f2bf(bacc[n][q]);

  f32x4 oacc[4] = {};
  #pragma unroll
  for (int dn = 0; dn < 4; ++dn) {
    const size_t mb = (size_t)(bh * NCHK + c) * 1024 + (size_t)(dn * 16 + lr) * 16 + (lg & 1) * 8;
    short8 bmv = *(const short8*)&Tvb[mb];
    short8 bm = (lg < 2) ? bmv : zero8;
    oacc[dn] = __builtin_amdgcn_mfma_f32_16x16x32_bf16(ga, bm, oacc[dn], 0, 0, 0);
  }
  for (int ks = 0; ks < nsl; ++ks) {
    short8 ab = *(const short8*)&Ab[ws + lr][ks * 32 + lg * 8];
    #pragma unroll
    for (int dn = 0; dn < 4; ++dn) {
      short8 bv = *(const short8*)&VT[dn * 16 + lr][ks * 32 + lg * 8];
      oacc[dn] = __builtin_amdgcn_mfma_f32_16x16x32_bf16(ab, bv, oacc[dn], 0, 0, 0);
    }
  }

  __syncthreads();
  unsigned short* ot = &VT[0][0];
  #pragma unroll
  for (int dn = 0; dn < 4; ++dn)
    #pragma unroll
    for (int q = 0; q < 4; ++q)
      ot[(ws + lg * 4 + q) * 64 + dn * 16 + lr] = f2bf(oacc[dn][q]);
  __syncthreads();
  {
    const int row = t >> 2, ch = (t & 3) * 2;
    const size_t gbase = ((size_t)(i0 + row) * BATCH + ib) * EMB + h * HD;
    *(uint4*)&outpre[gbase + ch * 8] = *(const uint4*)&ot[row * 64 + ch * 8];
    *(uint4*)&outpre[gbase + (ch + 1) * 8] = *(const uint4*)&ot[row * 64 + (ch + 1) * 8];
  }
}

// ---------------- O-GEMM (128x64, dbuf, f32 out) + aw mean over heads (bf16 in) ----------------
__global__ __launch_bounds__(256) void o_aw_kernel(
    const unsigned short* __restrict__ Xb, const unsigned short* __restrict__ Wb,
    const float* __restrict__ bias, float* __restrict__ Yf,
    const unsigned short* __restrict__ aw_bufb, float* __restrict__ out_aw)
{
  __shared__ unsigned short As[2][4096];
  __shared__ unsigned short Bs[2][2048];
  const int L = blockIdx.x, t = threadIdx.x;
  if (L < 512) {
    const int b = (L & 7) * 64 + (L >> 3);
    const int m0 = (b >> 4) * 128, n0 = (b & 15) * 64;
    const int lane = t & 63, w = t >> 6, wr = w >> 1, wc = w & 1;
    const int lr = lane & 15, lg = lane >> 4;
    const int srow = t >> 2, scol = (t & 3) << 3;
    const unsigned short* xa = &Xb[(size_t)(m0 + srow) * 1024 + scol];
    const unsigned short* xc = &Xb[(size_t)(m0 + srow + 64) * 1024 + scol];
    const unsigned short* wp = &Wb[(size_t)(n0 + srow) * 1024 + scol];
    f32x4 acc[4][2] = {};

    gload16(xa, &As[0][t * 8]);
    gload16(xc, &As[0][2048 + t * 8]);
    gload16(wp, &Bs[0][t * 8]);
    __syncthreads();
    int cur = 0;
    for (int ks = 0; ks < 32; ++ks) {
      if (ks < 31) {
        const int k1 = (ks + 1) * 32;
        gload16(xa + k1, &As[cur ^ 1][t * 8]);
        gload16(xc + k1, &As[cur ^ 1][2048 + t * 8]);
        gload16(wp + k1, &Bs[cur ^ 1][t * 8]);
      }
      short8 av[4], bv[2];
      #pragma unroll
      for (int m = 0; m < 4; ++m) av[m] = *(const short8*)&As[cur][(wr * 64 + m * 16 + lr) * 32 + lg * 8];
      #pragma unroll
      for (int n = 0; n < 2; ++n) bv[n] = *(const short8*)&Bs[cur][(wc * 32 + n * 16 + lr) * 32 + lg * 8];
      #pragma unroll
      for (int m = 0; m < 4; ++m)
        #pragma unroll
        for (int n = 0; n < 2; ++n)
          acc[m][n] = __builtin_amdgcn_mfma_f32_16x16x32_bf16(av[m], bv[n], acc[m][n], 0, 0, 0);
      __syncthreads();
      cur ^= 1;
    }
    #pragma unroll
    for (int n = 0; n < 2; ++n) {
      const int gcol = n0 + wc * 32 + n * 16 + lr;
      const float bcol = bias[gcol];
      #pragma unroll
      for (int m = 0; m < 4; ++m) {
        const int row0 = m0 + wr * 64 + m * 16 + lg * 4;
        #pragma unroll
        for (int q = 0; q < 4; ++q)
          Yf[(size_t)(row0 + q) * 1024 + gcol] = acc[m][n][q] + bcol;
      }
    }
  } else {
    const int idx = (L - 512) * 256 + t;
    const int p = idx & 15;
    const int i = (idx >> 4) & 2047;
    const int ib = idx >> 15;
    float s = 0.f;
    for (int hh = 0; hh < NH; ++hh)
      s += bf2f(aw_bufb[((size_t)(ib * NH + hh) * N_TOK + i) * NP + p]);
    out_aw[idx] = s * (1.f / 16.f);
  }
}

extern "C" void kernel_launch(void* const* d_in, const int* in_sizes, int n_in,
                              void* d_out, int out_size, void* d_ws, size_t ws_size,
                              hipStream_t stream) {
  const float* query  = (const float*)d_in[0];
  const float* pquery = (const float*)d_in[1];
  const float* Wpq    = (const float*)d_in[2];
  const float* bpq    = (const float*)d_in[3];
  const float* Wk     = (const float*)d_in[4];
  const float* bk     = (const float*)d_in[5];
  const float* Wv     = (const float*)d_in[6];
  const float* bv     = (const float*)d_in[7];
  const float* Wo     = (const float*)d_in[8];
  const float* bo     = (const float*)d_in[9];
  float* out = (float*)d_out;
  float* ws  = (float*)d_ws;

  float* Ts     = ws;                       // 16384
  float* bkv    = Ts + 16384;               // 2048
  unsigned* cnt = (unsigned*)(bkv + 2048);  // 32 (+pad to 512)
  unsigned short* Tkb   = (unsigned short*)(bkv + 2048 + 512);  // 1048576 bf16
  unsigned short* Tvb   = Tkb + 1048576;    // 1048576 bf16
  unsigned short* pq_sb = Tvb + 1048576;    // 32768 bf16
  unsigned short* peb   = pq_sb + 32768;    // 1048576 bf16
  unsigned short* awb   = peb + 1048576;    // 1048576 bf16
  unsigned short* qbf   = awb + 1048576;
  unsigned short* Kbf   = qbf + 4194304;
  unsigned short* Vbf   = Kbf + 4194304;
  unsigned short* wkvbf = Vbf + 4194304;    // 2097152
  unsigned short* wobf  = wkvbf + 2097152;  // 1048576
  unsigned short* opbf  = wobf + 1048576;   // 4194304

  prep_pq_kernel<<<1536, 256, 0, stream>>>(query, Wk, Wv, Wo, bk, bv, pquery, Wpq, bpq,
                                           qbf, wkvbf, wobf, bkv, pq_sb, cnt);
  kv_gemm_kernel<<<512, 256, 0, stream>>>(qbf, wkvbf, bkv, Kbf, Vbf);
  pattn_totals_kernel<<<dim3(NCHK, BHN), 256, 0, stream>>>(qbf, pq_sb, Kbf, Vbf,
                                                           peb, Tkb, Tvb, Ts, cnt);
  attn_mfma_kernel<<<dim3(NCHK, BHN), 256, 0, stream>>>(qbf, Kbf, Vbf, peb, Tkb, Tvb, Ts,
                                                        awb, opbf);
  o_aw_kernel<<<768, 256, 0, stream>>>(opbf, wobf, bo, out, awb, out + 4194304);
}

// Round 17
// 107.332 us; speedup vs baseline: 1.5613x; 1.5613x over previous
//
#include <hip/hip_runtime.h>
#include <cstddef>

#define N_TOK 2048
#define BATCH 2
#define EMB   1024
#define NH    16
#define HD    64
#define NP    16
#define BHN   32
#define CHK   64
#define NCHK  32
#define SCALING 0.125f

typedef __attribute__((ext_vector_type(8))) short short8;
typedef __attribute__((ext_vector_type(4))) float f32x4;

typedef __attribute__((address_space(1))) const void gvoid;
typedef __attribute__((address_space(3))) void lvoid;
__device__ __forceinline__ void gload16(const void* g, void* l) {
  __builtin_amdgcn_global_load_lds((gvoid*)g, (lvoid*)l, 16, 0, 0);
}

__device__ __forceinline__ unsigned short f2bf(float f) {
  unsigned u = __float_as_uint(f);
  u += 0x7FFFu + ((u >> 16) & 1u);
  return (unsigned short)(u >> 16);
}
__device__ __forceinline__ float bf2f(unsigned short b) {
  return __uint_as_float((unsigned)b << 16);
}

// ---------------- L1: fused prep (bf16 converts + concat) + pq projection ----------------
__global__ __launch_bounds__(256) void prep_pq_kernel(
    const float* __restrict__ query, const float* __restrict__ Wk,
    const float* __restrict__ Wv, const float* __restrict__ Wo,
    const float* __restrict__ bk, const float* __restrict__ bv,
    const float* __restrict__ pquery, const float* __restrict__ Wpq,
    const float* __restrict__ bpq,
    unsigned short* __restrict__ qbf, unsigned short* __restrict__ wkvbf,
    unsigned short* __restrict__ wobf, float* __restrict__ bkv,
    unsigned short* __restrict__ pq_sb)
{
  const int b = blockIdx.x, t = threadIdx.x;
  if (b < 512) {
    __shared__ float xs[EMB];
    __shared__ float part[4][64];
    const int r = b >> 4, seg = b & 15;
    const int p = r >> 1, ib = r & 1;
    const int el = t & 63, ks = t >> 6;
    const int e = seg * 64 + el;
    for (int l = t; l < EMB; l += 256) xs[l] = pquery[(size_t)r * EMB + l];
    __syncthreads();
    const float* wrow = &Wpq[(size_t)e * EMB + ks * 256];
    const float* xp = &xs[ks * 256];
    float acc = 0.f;
    #pragma unroll 8
    for (int cc = 0; cc < 256; cc += 4) {
      const float4 w4 = *(const float4*)&wrow[cc];
      acc += xp[cc] * w4.x + xp[cc + 1] * w4.y + xp[cc + 2] * w4.z + xp[cc + 3] * w4.w;
    }
    part[ks][el] = acc;
    __syncthreads();
    if (ks == 0) {
      float s = part[0][el] + part[1][el] + part[2][el] + part[3][el];
      s = (s + bpq[e]) * SCALING;
      const int h = e >> 6, d = e & 63;
      pq_sb[((size_t)(ib * NH + h) * NP + p) * HD + d] = f2bf(s);
    }
  } else {
    const int tid = (b - 512) * 256 + t;
    const int NT = 1024 * 256;
    for (int i = tid; i < 1835008; i += NT) {
      const float* src; unsigned short* dst; int off;
      if (i < 1048576)      { src = query; dst = qbf;             off = i; }
      else if (i < 1310720) { src = Wk;    dst = wkvbf;           off = i - 1048576; }
      else if (i < 1572864) { src = Wv;    dst = wkvbf + 1048576; off = i - 1310720; }
      else                  { src = Wo;    dst = wobf;            off = i - 1572864; }
      const float4 v = *(const float4*)&src[(size_t)off * 4];
      ushort4 o;
      o.x = f2bf(v.x); o.y = f2bf(v.y); o.z = f2bf(v.z); o.w = f2bf(v.w);
      *(ushort4*)&dst[(size_t)off * 4] = o;
    }
    if (tid < 512) {
      const int j = tid * 4;
      if (j < 1024) *(float4*)&bkv[j] = *(const float4*)&bk[j];
      else          *(float4*)&bkv[j] = *(const float4*)&bv[j - 1024];
    }
  }
}

// ---------------- KV GEMM: 128x128 tiles, double-buffered, dual bf16 out ----------------
__global__ __launch_bounds__(256) void kv_gemm_kernel(
    const unsigned short* __restrict__ Xb, const unsigned short* __restrict__ Wb,
    const float* __restrict__ bias, unsigned short* __restrict__ Y0,
    unsigned short* __restrict__ Y1)
{
  __shared__ unsigned short As[2][4096];
  __shared__ unsigned short Bs[2][4096];
  const int t = threadIdx.x;
  const int L = blockIdx.x;
  const int b = (L & 7) * 64 + (L >> 3);            // XCD-bijective swizzle (512 % 8 == 0)
  const int m0 = (b >> 4) * 128, n0 = (b & 15) * 128;
  const int lane = t & 63, w = t >> 6, wr = w >> 1, wc = w & 1;
  const int lr = lane & 15, lg = lane >> 4;
  const int srow = t >> 2, scol = (t & 3) << 3;
  const unsigned short* xa = &Xb[(size_t)(m0 + srow) * 1024 + scol];
  const unsigned short* xc = xa + (size_t)64 * 1024;
  const unsigned short* wp = &Wb[(size_t)(n0 + srow) * 1024 + scol];
  const unsigned short* wq = wp + (size_t)64 * 1024;
  f32x4 acc[4][4] = {};

  gload16(xa, &As[0][t * 8]);
  gload16(xc, &As[0][2048 + t * 8]);
  gload16(wp, &Bs[0][t * 8]);
  gload16(wq, &Bs[0][2048 + t * 8]);
  __syncthreads();
  int cur = 0;
  for (int ks = 0; ks < 32; ++ks) {
    if (ks < 31) {
      const int k1 = (ks + 1) * 32;
      gload16(xa + k1, &As[cur ^ 1][t * 8]);
      gload16(xc + k1, &As[cur ^ 1][2048 + t * 8]);
      gload16(wp + k1, &Bs[cur ^ 1][t * 8]);
      gload16(wq + k1, &Bs[cur ^ 1][2048 + t * 8]);
    }
    short8 av[4], bv[4];
    #pragma unroll
    for (int m = 0; m < 4; ++m) av[m] = *(const short8*)&As[cur][(wr * 64 + m * 16 + lr) * 32 + lg * 8];
    #pragma unroll
    for (int n = 0; n < 4; ++n) bv[n] = *(const short8*)&Bs[cur][(wc * 64 + n * 16 + lr) * 32 + lg * 8];
    #pragma unroll
    for (int m = 0; m < 4; ++m)
      #pragma unroll
      for (int n = 0; n < 4; ++n)
        acc[m][n] = __builtin_amdgcn_mfma_f32_16x16x32_bf16(av[m], bv[n], acc[m][n], 0, 0, 0);
    __syncthreads();
    cur ^= 1;
  }

  unsigned short* dst = (n0 < 1024) ? Y0 : Y1;
  #pragma unroll
  for (int n = 0; n < 4; ++n) {
    const int gcol = n0 + wc * 64 + n * 16 + lr;
    const float bcol = bias[gcol];
    const int lcol = gcol & 1023;
    #pragma unroll
    for (int m = 0; m < 4; ++m) {
      const int row0 = m0 + wr * 64 + m * 16 + lg * 4;
      #pragma unroll
      for (int q = 0; q < 4; ++q)
        dst[(size_t)(row0 + q) * 1024 + lcol] = f2bf(acc[m][n][q] + bcol);
    }
  }
}

// ---------------- fused pattn (MFMA logits) + exp + per-chunk totals (bf16 out) ----------------
__global__ __launch_bounds__(256) void pattn_totals_kernel(
    const unsigned short* __restrict__ qbf, const unsigned short* __restrict__ pq_sb,
    const unsigned short* __restrict__ Kbf, const unsigned short* __restrict__ Vbf,
    unsigned short* __restrict__ peb, unsigned short* __restrict__ Tkb,
    unsigned short* __restrict__ Tvb, float* __restrict__ Tsc)
{
  const int c = blockIdx.x, bh = blockIdx.y;
  const int ib = bh >> 4, h = bh & 15;
  const int t = threadIdx.x;
  const int i0 = c * CHK;
  const int lane = t & 63, w = t >> 6;
  const int lr = lane & 15, lg = lane >> 4;
  const int wrow = w * 16;

  __shared__ unsigned short KT[64][80];   // [d][j]
  __shared__ unsigned short VT[64][80];   // [d][j]
  __shared__ unsigned short EbT[16][80];  // [p][j]
  __shared__ float Ef[64][20];            // [j][p]
  __shared__ float tspart[4][16];

  #pragma unroll
  for (int it = 0; it < 2; ++it) {
    const int task = t + it * 256;
    const int j = task & 63, dg = task >> 6;
    const size_t g = ((size_t)(i0 + j) * BATCH + ib) * EMB + h * HD + dg * 8;
    const uint4 ku = *(const uint4*)&Kbf[g];
    const uint4 vu = *(const uint4*)&Vbf[g];
    const unsigned short* kk = (const unsigned short*)&ku;
    const unsigned short* vv = (const unsigned short*)&vu;
    #pragma unroll
    for (int e = 0; e < 8; ++e) { KT[dg * 8 + e][j] = kk[e]; VT[dg * 8 + e][j] = vv[e]; }
  }

  // logits via MFMA
  {
    const size_t qg = ((size_t)(i0 + wrow + lr) * BATCH + ib) * EMB + h * HD;
    short8 avq0 = *(const short8*)&qbf[qg + lg * 8];
    short8 avq1 = *(const short8*)&qbf[qg + 32 + lg * 8];
    const size_t pb = (size_t)bh * 1024 + (size_t)lr * 64;
    short8 bp0 = *(const short8*)&pq_sb[pb + lg * 8];
    short8 bp1 = *(const short8*)&pq_sb[pb + 32 + lg * 8];
    f32x4 lacc = {};
    lacc = __builtin_amdgcn_mfma_f32_16x16x32_bf16(avq0, bp0, lacc, 0, 0, 0);
    lacc = __builtin_amdgcn_mfma_f32_16x16x32_bf16(avq1, bp1, lacc, 0, 0, 0);
    #pragma unroll
    for (int q = 0; q < 4; ++q) {
      const int i = wrow + lg * 4 + q;
      const float e = expf(lacc[q]);
      const unsigned short eb = f2bf(e);
      peb[(size_t)bh * (N_TOK * NP) + (size_t)(i0 + i) * NP + lr] = eb;
      Ef[i][lr] = e;
      EbT[lr][i] = eb;
    }
  }
  __syncthreads();

  if (t < 64) {
    const int p = t & 15, qq = t >> 4;
    float s = 0.f;
    #pragma unroll
    for (int jj = 0; jj < 16; ++jj) s += Ef[qq * 16 + jj][p];
    tspart[qq][p] = s;
  }

  short8 ae0 = *(const short8*)&EbT[lr][lg * 8];
  short8 ae1 = *(const short8*)&EbT[lr][32 + lg * 8];
  const size_t tb = (size_t)(bh * NCHK + c) * 1024;

  {  // Tk raw, [p][d] layout, bf16
    f32x4 ka = {};
    short8 bk0 = *(const short8*)&KT[w * 16 + lr][lg * 8];
    short8 bk1 = *(const short8*)&KT[w * 16 + lr][32 + lg * 8];
    ka = __builtin_amdgcn_mfma_f32_16x16x32_bf16(ae0, bk0, ka, 0, 0, 0);
    ka = __builtin_amdgcn_mfma_f32_16x16x32_bf16(ae1, bk1, ka, 0, 0, 0);
    #pragma unroll
    for (int q = 0; q < 4; ++q) Tkb[tb + (lg * 4 + q) * 64 + w * 16 + lr] = f2bf(ka[q]);
  }
  {  // Tv raw, [d][p] layout, bf16
    f32x4 va = {};
    short8 av0 = *(const short8*)&VT[w * 16 + lr][lg * 8];
    short8 av1 = *(const short8*)&VT[w * 16 + lr][32 + lg * 8];
    va = __builtin_amdgcn_mfma_f32_16x16x32_bf16(av0, ae0, va, 0, 0, 0);
    va = __builtin_amdgcn_mfma_f32_16x16x32_bf16(av1, ae1, va, 0, 0, 0);
    #pragma unroll
    for (int q = 0; q < 4; ++q) Tvb[tb + (w * 16 + lg * 4 + q) * 16 + lr] = f2bf(va[q]);
  }
  __syncthreads();
  if (t < 16)
    Tsc[(size_t)(bh * NCHK + c) * 16 + t] =
        tspart[0][t] + tspart[1][t] + tspart[2][t] + tspart[3][t];
}

// ---------------- exclusive scan over chunks (bf16 Tk/Tv, f32 accumulate) ----------------
__global__ __launch_bounds__(256) void chunk_scan_kernel(
    unsigned short* __restrict__ Tkb, unsigned short* __restrict__ Tvb,
    float* __restrict__ Ts)
{
  const int bh = blockIdx.x, y = blockIdx.y, t = threadIdx.x;
  const int slot = y * 256 + t;
  unsigned short* arr = (slot < 1024) ? Tkb : Tvb;
  const int e = slot & 1023;
  const size_t base = (size_t)bh * (NCHK * 1024) + e;
  float v[NCHK];
  #pragma unroll
  for (int c = 0; c < NCHK; ++c) v[c] = bf2f(arr[base + (size_t)c * 1024]);
  float run = 0.f;
  #pragma unroll
  for (int c = 0; c < NCHK; ++c) { arr[base + (size_t)c * 1024] = f2bf(run); run += v[c]; }
  if (y == 7 && t < 16) {
    const size_t sb = (size_t)bh * (NCHK * 16) + t;
    float s[NCHK];
    #pragma unroll
    for (int c = 0; c < NCHK; ++c) s[c] = Ts[sb + c * 16];
    float rs = 0.f;
    #pragma unroll
    for (int c = 0; c < NCHK; ++c) { Ts[sb + c * 16] = rs; rs += s[c]; }
  }
}

// ---------------- within-chunk causal attention via MFMA (register-direct operands) ----------------
__global__ __launch_bounds__(256) void attn_mfma_kernel(
    const unsigned short* __restrict__ qbf, const unsigned short* __restrict__ Kbf,
    const unsigned short* __restrict__ Vbf, const unsigned short* __restrict__ peb,
    const unsigned short* __restrict__ Tkb, const unsigned short* __restrict__ Tvb,
    const float* __restrict__ Ts, unsigned short* __restrict__ aw_bufb,
    unsigned short* __restrict__ outpre)
{
  const int c = blockIdx.x, bh = blockIdx.y;
  const int ib = bh >> 4, h = bh & 15;
  const int t = threadIdx.x;
  const int i0 = c * CHK;
  const int lane = t & 63, w = t >> 6;
  const int ws = w * 16;
  const int lr = lane & 15, lg = lane >> 4;
  const int nsl = (w >> 1) + 1;
  const short8 zero8 = {0, 0, 0, 0, 0, 0, 0, 0};

  __shared__ unsigned short VT[64][80];    // [d][j]
  __shared__ unsigned short Ab[64][80];    // masked S / B per-wave strips
  __shared__ unsigned short EbT[16][80];   // [p][j]
  __shared__ unsigned short Gb[64][40];    // [i][p] padded

  // Q fragment direct from global
  const size_t qg = ((size_t)(i0 + ws + lr) * BATCH + ib) * EMB + h * HD;
  short8 avq0 = *(const short8*)&qbf[qg + lg * 8];
  short8 avq1 = *(const short8*)&qbf[qg + 32 + lg * 8];

  #pragma unroll
  for (int it = 0; it < 2; ++it) {
    const int task = t + it * 256;
    const int j = task & 63, dg = task >> 6;
    const size_t g = ((size_t)(i0 + j) * BATCH + ib) * EMB + h * HD + dg * 8;
    const uint4 vu = *(const uint4*)&Vbf[g];
    const unsigned short* vv = (const unsigned short*)&vu;
    #pragma unroll
    for (int e = 0; e < 8; ++e) VT[dg * 8 + e][j] = vv[e];
  }
  {
    const int j = t >> 2, p0 = (t & 3) << 2;
    const ushort4 e4 = *(const ushort4*)&peb[(size_t)bh * (N_TOK * NP) + (size_t)(i0 + j) * NP + p0];
    EbT[p0][j] = e4.x; EbT[p0 + 1][j] = e4.y; EbT[p0 + 2][j] = e4.z; EbT[p0 + 3][j] = e4.w;
  }
  __syncthreads();

  // ---- S = Q@K^T, K fragments direct from global (unrolled, guarded MFMA)
  f32x4 sacc[4] = {};
  #pragma unroll
  for (int n = 0; n < 4; ++n) {
    const size_t kg = ((size_t)(i0 + n * 16 + lr) * BATCH + ib) * EMB + h * HD;
    short8 bk0 = *(const short8*)&Kbf[kg + lg * 8];
    short8 bk1 = *(const short8*)&Kbf[kg + 32 + lg * 8];
    if (n <= w) {
      sacc[n] = __builtin_amdgcn_mfma_f32_16x16x32_bf16(avq0, bk0, sacc[n], 0, 0, 0);
      sacc[n] = __builtin_amdgcn_mfma_f32_16x16x32_bf16(avq1, bk1, sacc[n], 0, 0, 0);
    }
  }
  #pragma unroll
  for (int q = 0; q < 4; ++q)
    if (lr >= lg * 4 + q) sacc[w][q] = 0.f;
  for (int n = 0; n < 2 * nsl; ++n)
    #pragma unroll
    for (int q = 0; q < 4; ++q)
      Ab[ws + lg * 4 + q][n * 16 + lr] = f2bf(sacc[n][q]);

  short8 bve0 = *(const short8*)&EbT[lr][lg * 8];
  short8 bve1 = *(const short8*)&EbT[lr][32 + lg * 8];

  // ---- W1 = Q@Nb (Tkb direct, bf16) + S_masked@E
  f32x4 wacc = {};
  {
    const size_t nb = (size_t)(bh * NCHK + c) * 1024 + (size_t)lr * 64 + lg * 8;
    short8 bn0 = *(const short8*)&Tkb[nb];
    short8 bn1 = *(const short8*)&Tkb[nb + 32];
    wacc = __builtin_amdgcn_mfma_f32_16x16x32_bf16(avq0, bn0, wacc, 0, 0, 0);
    wacc = __builtin_amdgcn_mfma_f32_16x16x32_bf16(avq1, bn1, wacc, 0, 0, 0);
  }
  for (int ks = 0; ks < nsl; ++ks) {
    short8 aa = *(const short8*)&Ab[ws + lr][ks * 32 + lg * 8];
    wacc = __builtin_amdgcn_mfma_f32_16x16x32_bf16(aa, ks ? bve1 : bve0, wacc, 0, 0, 0);
  }
  const float s0 = Ts[(size_t)(bh * NCHK + c) * 16 + lr];
  f32x4 scacc = {s0, s0, s0, s0};
  for (int ks = 0; ks < nsl; ++ks) {
    const int jb = ks * 32 + lg * 8;
    const int irow = ws + lr;
    short8 ones;
    #pragma unroll
    for (int e = 0; e < 8; ++e) ones[e] = (short)((jb + e < irow) ? 0x3F80 : 0);
    scacc = __builtin_amdgcn_mfma_f32_16x16x32_bf16(ones, ks ? bve1 : bve0, scacc, 0, 0, 0);
  }

  // ---- finalize: softmax over p, write aw (bf16), stage G
  const size_t awbase = (size_t)bh * (N_TOK * NP) + (size_t)i0 * NP;
  #pragma unroll
  for (int q = 0; q < 4; ++q) {
    const int il = lg * 4 + q;
    const float ssum = scacc[q];
    const float ssafe = (ssum > 0.f) ? ssum : 1.f;
    const float wv = SCALING * wacc[q] / ssafe;
    float m = wv;
    #pragma unroll
    for (int off = 1; off < 16; off <<= 1) m = fmaxf(m, __shfl_xor(m, off, 64));
    const float e = expf(wv - m);
    float ss = e;
    #pragma unroll
    for (int off = 1; off < 16; off <<= 1) ss += __shfl_xor(ss, off, 64);
    const float aw = e / ss;
    aw_bufb[awbase + (size_t)(ws + il) * NP + lr] = f2bf(aw);
    const float g = aw / ssafe;
    Gb[ws + il][lr] = f2bf(g);
    Gb[ws + il][lr + 16] = 0;
  }

  // ---- stage 2: B = G@E^T (E rows direct from peb), mask; out = G@Mb (Tvb direct) + B@V
  short8 ga = *(const short8*)&Gb[ws + lr][lg * 8];
  f32x4 bacc[4] = {};
  #pragma unroll
  for (int n = 0; n < 4; ++n) {
    const size_t eg = (size_t)bh * (N_TOK * NP) + (size_t)(i0 + n * 16 + lr) * NP + (lg & 1) * 8;
    short8 bl = *(const short8*)&peb[eg];
    short8 be = (lg < 2) ? bl : zero8;
    if (n <= w)
      bacc[n] = __builtin_amdgcn_mfma_f32_16x16x32_bf16(ga, be, bacc[n], 0, 0, 0);
  }
  #pragma unroll
  for (int q = 0; q < 4; ++q)
    if (lr >= lg * 4 + q) bacc[w][q] = 0.f;
  for (int n = 0; n < 2 * nsl; ++n)
    #pragma unroll
    for (int q = 0; q < 4; ++q)
      Ab[ws + lg * 4 + q][n * 16 + lr] = f2bf(bacc[n][q]);

  f32x4 oacc[4] = {};
  #pragma unroll
  for (int dn = 0; dn < 4; ++dn) {
    const size_t mb = (size_t)(bh * NCHK + c) * 1024 + (size_t)(dn * 16 + lr) * 16 + (lg & 1) * 8;
    short8 bmv = *(const short8*)&Tvb[mb];
    short8 bm = (lg < 2) ? bmv : zero8;
    oacc[dn] = __builtin_amdgcn_mfma_f32_16x16x32_bf16(ga, bm, oacc[dn], 0, 0, 0);
  }
  for (int ks = 0; ks < nsl; ++ks) {
    short8 ab = *(const short8*)&Ab[ws + lr][ks * 32 + lg * 8];
    #pragma unroll
    for (int dn = 0; dn < 4; ++dn) {
      short8 bv = *(const short8*)&VT[dn * 16 + lr][ks * 32 + lg * 8];
      oacc[dn] = __builtin_amdgcn_mfma_f32_16x16x32_bf16(ab, bv, oacc[dn], 0, 0, 0);
    }
  }

  #pragma unroll
  for (int dn = 0; dn < 4; ++dn)
    #pragma unroll
    for (int q = 0; q < 4; ++q) {
      const int i = ws + lg * 4 + q;
      const int d = dn * 16 + lr;
      outpre[((size_t)(i0 + i) * BATCH + ib) * EMB + h * HD + d] = f2bf(oacc[dn][q]);
    }
}

// ---------------- O-GEMM (128x64, dbuf, f32 out) + aw mean over heads (bf16 in) ----------------
__global__ __launch_bounds__(256) void o_aw_kernel(
    const unsigned short* __restrict__ Xb, const unsigned short* __restrict__ Wb,
    const float* __restrict__ bias, float* __restrict__ Yf,
    const unsigned short* __restrict__ aw_bufb, float* __restrict__ out_aw)
{
  __shared__ unsigned short As[2][4096];
  __shared__ unsigned short Bs[2][2048];
  const int L = blockIdx.x, t = threadIdx.x;
  if (L < 512) {
    const int b = (L & 7) * 64 + (L >> 3);
    const int m0 = (b >> 4) * 128, n0 = (b & 15) * 64;
    const int lane = t & 63, w = t >> 6, wr = w >> 1, wc = w & 1;
    const int lr = lane & 15, lg = lane >> 4;
    const int srow = t >> 2, scol = (t & 3) << 3;
    const unsigned short* xa = &Xb[(size_t)(m0 + srow) * 1024 + scol];
    const unsigned short* xc = &Xb[(size_t)(m0 + srow + 64) * 1024 + scol];
    const unsigned short* wp = &Wb[(size_t)(n0 + srow) * 1024 + scol];
    f32x4 acc[4][2] = {};

    gload16(xa, &As[0][t * 8]);
    gload16(xc, &As[0][2048 + t * 8]);
    gload16(wp, &Bs[0][t * 8]);
    __syncthreads();
    int cur = 0;
    for (int ks = 0; ks < 32; ++ks) {
      if (ks < 31) {
        const int k1 = (ks + 1) * 32;
        gload16(xa + k1, &As[cur ^ 1][t * 8]);
        gload16(xc + k1, &As[cur ^ 1][2048 + t * 8]);
        gload16(wp + k1, &Bs[cur ^ 1][t * 8]);
      }
      short8 av[4], bv[2];
      #pragma unroll
      for (int m = 0; m < 4; ++m) av[m] = *(const short8*)&As[cur][(wr * 64 + m * 16 + lr) * 32 + lg * 8];
      #pragma unroll
      for (int n = 0; n < 2; ++n) bv[n] = *(const short8*)&Bs[cur][(wc * 32 + n * 16 + lr) * 32 + lg * 8];
      #pragma unroll
      for (int m = 0; m < 4; ++m)
        #pragma unroll
        for (int n = 0; n < 2; ++n)
          acc[m][n] = __builtin_amdgcn_mfma_f32_16x16x32_bf16(av[m], bv[n], acc[m][n], 0, 0, 0);
      __syncthreads();
      cur ^= 1;
    }
    #pragma unroll
    for (int n = 0; n < 2; ++n) {
      const int gcol = n0 + wc * 32 + n * 16 + lr;
      const float bcol = bias[gcol];
      #pragma unroll
      for (int m = 0; m < 4; ++m) {
        const int row0 = m0 + wr * 64 + m * 16 + lg * 4;
        #pragma unroll
        for (int q = 0; q < 4; ++q)
          Yf[(size_t)(row0 + q) * 1024 + gcol] = acc[m][n][q] + bcol;
      }
    }
  } else {
    const int idx = (L - 512) * 256 + t;
    const int p = idx & 15;
    const int i = (idx >> 4) & 2047;
    const int ib = idx >> 15;
    float s = 0.f;
    for (int hh = 0; hh < NH; ++hh)
      s += bf2f(aw_bufb[((size_t)(ib * NH + hh) * N_TOK + i) * NP + p]);
    out_aw[idx] = s * (1.f / 16.f);
  }
}

extern "C" void kernel_launch(void* const* d_in, const int* in_sizes, int n_in,
                              void* d_out, int out_size, void* d_ws, size_t ws_size,
                              hipStream_t stream) {
  const float* query  = (const float*)d_in[0];
  const float* pquery = (const float*)d_in[1];
  const float* Wpq    = (const float*)d_in[2];
  const float* bpq    = (const float*)d_in[3];
  const float* Wk     = (const float*)d_in[4];
  const float* bk     = (const float*)d_in[5];
  const float* Wv     = (const float*)d_in[6];
  const float* bv     = (const float*)d_in[7];
  const float* Wo     = (const float*)d_in[8];
  const float* bo     = (const float*)d_in[9];
  float* out = (float*)d_out;
  float* ws  = (float*)d_ws;

  float* Ts     = ws;                       // 16384
  float* bkv    = Ts + 16384;               // 2048
  unsigned short* Tkb   = (unsigned short*)(bkv + 2048);   // 1048576 bf16
  unsigned short* Tvb   = Tkb + 1048576;    // 1048576 bf16
  unsigned short* pq_sb = Tvb + 1048576;    // 32768 bf16
  unsigned short* peb   = pq_sb + 32768;    // 1048576 bf16
  unsigned short* awb   = peb + 1048576;    // 1048576 bf16
  unsigned short* qbf   = awb + 1048576;
  unsigned short* Kbf   = qbf + 4194304;
  unsigned short* Vbf   = Kbf + 4194304;
  unsigned short* wkvbf = Vbf + 4194304;    // 2097152
  unsigned short* wobf  = wkvbf + 2097152;  // 1048576
  unsigned short* opbf  = wobf + 1048576;   // 4194304

  prep_pq_kernel<<<1536, 256, 0, stream>>>(query, Wk, Wv, Wo, bk, bv, pquery, Wpq, bpq,
                                           qbf, wkvbf, wobf, bkv, pq_sb);
  kv_gemm_kernel<<<512, 256, 0, stream>>>(qbf, wkvbf, bkv, Kbf, Vbf);
  pattn_totals_kernel<<<dim3(NCHK, BHN), 256, 0, stream>>>(qbf, pq_sb, Kbf, Vbf,
                                                           peb, Tkb, Tvb, Ts);
  chunk_scan_kernel<<<dim3(BHN, 8), 256, 0, stream>>>(Tkb, Tvb, Ts);
  attn_mfma_kernel<<<dim3(NCHK, BHN), 256, 0, stream>>>(qbf, Kbf, Vbf, peb, Tkb, Tvb, Ts,
                                                        awb, opbf);
  o_aw_kernel<<<768, 256, 0, stream>>>(opbf, wobf, bo, out, awb, out + 4194304);
}